// Round 1
// baseline (699.046 us; speedup 1.0000x reference)
//
#include <hip/hip_runtime.h>
#include <hip/hip_bf16.h>
#include <stdint.h>

#define BATCH 16
#define CDIM  512
#define DDIM  4096

typedef short bf16x8 __attribute__((ext_vector_type(8)));
typedef float f32x4  __attribute__((ext_vector_type(4)));

static __device__ __forceinline__ uint32_t pack2bf(float lo, float hi) {
  __hip_bfloat162 h2 = __float22bfloat162_rn(make_float2(lo, hi));
  uint32_t u; __builtin_memcpy(&u, &h2, 4); return u;
}

// ---------------------------------------------------------------------------
// Phase 1: S[b][c][e] = (1/64) * sum_d Q[b][c][d] * K[b][e][d]
// 128x128 tile per block, BK=64, bf16 MFMA 16x16x32.
// LDS layout: row r holds 64 bf16 (128 B = 8 granules of 16 B);
// granule g stored at slot g ^ (r & 7)  -> conflict-free b128 frag reads.
// ---------------------------------------------------------------------------
__global__ __launch_bounds__(256) void gemm_qk(const float* __restrict__ Q,
                                               const float* __restrict__ K,
                                               float* __restrict__ S) {
  __shared__ __align__(16) char sA[16384];
  __shared__ __align__(16) char sB[16384];
  const int b    = blockIdx.z;
  const int c0   = blockIdx.y * 128;
  const int e0   = blockIdx.x * 128;
  const int t    = threadIdx.x;
  const int lane = t & 63;
  const int wave = t >> 6;
  const int wm = wave & 1, wn = wave >> 1;
  const int l15 = lane & 15, quad = lane >> 4;

  const float* Qb = Q + (size_t)b * CDIM * DDIM;
  const float* Kb = K + (size_t)b * CDIM * DDIM;

  f32x4 acc[4][4];
  const f32x4 zero = {0.f, 0.f, 0.f, 0.f};
#pragma unroll
  for (int i = 0; i < 4; i++)
#pragma unroll
    for (int j = 0; j < 4; j++) acc[i][j] = zero;

  const int h     = t & 15;   // half-granule (4 floats) within row
  const int rbase = t >> 4;   // 0..15

  for (int d0 = 0; d0 < DDIM; d0 += 64) {
#pragma unroll
    for (int pass = 0; pass < 8; pass++) {
      int r    = rbase + (pass << 4);           // 0..127
      int g    = h >> 1, half = h & 1;
      int off  = r * 128 + ((g ^ (r & 7)) << 4) + (half << 3);
      float4 qa = *(const float4*)(Qb + (size_t)(c0 + r) * DDIM + d0 + (h << 2));
      float4 kb = *(const float4*)(Kb + (size_t)(e0 + r) * DDIM + d0 + (h << 2));
      *(uint2*)(sA + off) = make_uint2(pack2bf(qa.x, qa.y), pack2bf(qa.z, qa.w));
      *(uint2*)(sB + off) = make_uint2(pack2bf(kb.x, kb.y), pack2bf(kb.z, kb.w));
    }
    __syncthreads();
#pragma unroll
    for (int kk = 0; kk < 2; kk++) {
      bf16x8 af[4], bfr[4];
#pragma unroll
      for (int mi = 0; mi < 4; mi++) {
        int r = wm * 64 + mi * 16 + l15;
        int g = kk * 4 + quad;
        af[mi] = *(const bf16x8*)(sA + r * 128 + ((g ^ (r & 7)) << 4));
      }
#pragma unroll
      for (int ni = 0; ni < 4; ni++) {
        int r = wn * 64 + ni * 16 + l15;
        int g = kk * 4 + quad;
        bfr[ni] = *(const bf16x8*)(sB + r * 128 + ((g ^ (r & 7)) << 4));
      }
#pragma unroll
      for (int mi = 0; mi < 4; mi++)
#pragma unroll
        for (int ni = 0; ni < 4; ni++)
          acc[mi][ni] = __builtin_amdgcn_mfma_f32_16x16x32_bf16(af[mi], bfr[ni], acc[mi][ni], 0, 0, 0);
    }
    __syncthreads();
  }

  float* Sb = S + (size_t)b * CDIM * CDIM;
#pragma unroll
  for (int mi = 0; mi < 4; mi++)
#pragma unroll
    for (int ni = 0; ni < 4; ni++) {
      int col = e0 + wn * 64 + ni * 16 + l15;
#pragma unroll
      for (int reg = 0; reg < 4; reg++) {
        int row = c0 + wm * 64 + mi * 16 + quad * 4 + reg;
        Sb[(size_t)row * CDIM + col] = acc[mi][ni][reg] * 0.015625f;  // 1/64 exact
      }
    }
}

// ---------------------------------------------------------------------------
// Phase 2a: row softmax of S -> P_a[b][c][e] (bf16). One block per row.
// ---------------------------------------------------------------------------
__global__ __launch_bounds__(256) void softmax_rows(const float* __restrict__ S,
                                                    __hip_bfloat16* __restrict__ P) {
  const int row = blockIdx.x;  // b*512 + c
  const float* Sr = S + (size_t)row * CDIM;
  const int t = threadIdx.x;
  float v0 = Sr[t], v1 = Sr[t + 256];
  float m = fmaxf(v0, v1);
#pragma unroll
  for (int off = 32; off > 0; off >>= 1) m = fmaxf(m, __shfl_down(m, off));
  __shared__ float red[8];
  if ((t & 63) == 0) red[t >> 6] = m;
  __syncthreads();
  m = fmaxf(fmaxf(red[0], red[1]), fmaxf(red[2], red[3]));
  float e0 = __expf(v0 - m), e1 = __expf(v1 - m);
  float s = e0 + e1;
#pragma unroll
  for (int off = 32; off > 0; off >>= 1) s += __shfl_down(s, off);
  if ((t & 63) == 0) red[4 + (t >> 6)] = s;
  __syncthreads();
  s = (red[4] + red[5]) + (red[6] + red[7]);
  float inv = 1.0f / s;
  P[(size_t)row * CDIM + t]       = __float2bfloat16(e0 * inv);
  P[(size_t)row * CDIM + t + 256] = __float2bfloat16(e1 * inv);
}

// ---------------------------------------------------------------------------
// Phase 2b: column softmax of S -> P_b[b][e][c] (bf16).
// Block = (16 columns e) x (512 rows c), column data cached in LDS.
// ---------------------------------------------------------------------------
__global__ __launch_bounds__(256) void softmax_cols(const float* __restrict__ S,
                                                    __hip_bfloat16* __restrict__ Pb) {
  __shared__ float col[512][17];
  __shared__ float red[16][17];
  __shared__ float invs[16];
  const int b  = blockIdx.y;
  const int e0 = blockIdx.x * 16;
  const int t  = threadIdx.x;
  const int ci = t & 15, ri = t >> 4;
  const float* Sb = S + (size_t)b * CDIM * CDIM + e0;

  float pmax = -1e30f;
#pragma unroll 4
  for (int it = 0; it < 32; it++) {
    int row = ri + (it << 4);
    float v = Sb[(size_t)row * CDIM + ci];
    col[row][ci] = v;
    pmax = fmaxf(pmax, v);
  }
  red[ri][ci] = pmax;
  __syncthreads();
  float M = red[0][ci];
#pragma unroll
  for (int k = 1; k < 16; k++) M = fmaxf(M, red[k][ci]);
  float psum = 0.f;
#pragma unroll 4
  for (int it = 0; it < 32; it++) {
    int row = ri + (it << 4);
    float ev = __expf(col[row][ci] - M);
    col[row][ci] = ev;
    psum += ev;
  }
  __syncthreads();               // protect red reuse
  red[ri][ci] = psum;
  __syncthreads();
  if (ri == 0) {
    float s = 0.f;
#pragma unroll
    for (int k = 0; k < 16; k++) s += red[k][ci];
    invs[ci] = 1.0f / s;
  }
  __syncthreads();
  __hip_bfloat16* Prow = Pb + ((size_t)b * CDIM + e0) * CDIM;
#pragma unroll
  for (int re = 0; re < 16; re++) {
    float inv = invs[re];
    Prow[(size_t)re * CDIM + t]       = __float2bfloat16(col[t][re] * inv);
    Prow[(size_t)re * CDIM + t + 256] = __float2bfloat16(col[t + 256][re] * inv);
  }
}

// ---------------------------------------------------------------------------
// Phase 3: out[b][m][d] = sum_e P[b][m][e] * V[b][e][d]
// dir 0: P=P_a, V=x2 (K), out=out_A.  dir 1: P=P_b, V=x1 (Q), out=out_B.
// V is transposed into LDS during staging as bf16 (e,e+1) pairs.
// ---------------------------------------------------------------------------
__global__ __launch_bounds__(256) void gemm_pv(const __hip_bfloat16* __restrict__ PaAll,
                                               const __hip_bfloat16* __restrict__ PbAll,
                                               const float* __restrict__ X1,
                                               const float* __restrict__ X2,
                                               float* __restrict__ out) {
  __shared__ __align__(16) char sP[16384];
  __shared__ __align__(16) char sV[16384];
  const int zz  = blockIdx.z;
  const int dir = zz & 1, b = zz >> 1;
  const int m0  = blockIdx.y * 128;
  const int d0b = blockIdx.x * 128;
  const int t    = threadIdx.x;
  const int lane = t & 63, wave = t >> 6;
  const int wm = wave & 1, wn = wave >> 1;
  const int l15 = lane & 15, quad = lane >> 4;

  const uint16_t* P = (const uint16_t*)(dir ? PbAll : PaAll) + (size_t)b * CDIM * CDIM;
  const float*    V = (dir ? X1 : X2) + (size_t)b * CDIM * DDIM;
  float*          O = out + (size_t)dir * ((size_t)BATCH * CDIM * DDIM) + (size_t)b * CDIM * DDIM;

  f32x4 acc[4][4];
  const f32x4 zero = {0.f, 0.f, 0.f, 0.f};
#pragma unroll
  for (int i = 0; i < 4; i++)
#pragma unroll
    for (int j = 0; j < 4; j++) acc[i][j] = zero;

  const int cl = t >> 3, gs = t & 7;                      // P staging
  const int dl = ((t & 15) << 2) + ((t >> 7) << 6);       // V staging: d base
  const int u  = (t >> 4) & 7;                            // V staging: e-pair group

  for (int e0 = 0; e0 < CDIM; e0 += 64) {
    // stage P tile: 128 rows(m) x 64 e bf16, xor-swizzled granules
#pragma unroll
    for (int j = 0; j < 4; j++) {
      int c  = cl + (j << 5);
      int gl = gs ^ (c & 7);
      uint4 v = *(const uint4*)(P + (size_t)(m0 + c) * CDIM + e0 + (gl << 3));
      *(uint4*)(sP + c * 128 + (gs << 4)) = v;
    }
    // stage V^T tile: row d (128) holds 64 e as bf16; pair (2p,2p+1) at word p
#pragma unroll
    for (int pass = 0; pass < 4; pass++) {
      int p = u + (pass << 3);               // e-pair index 0..31
      int e = e0 + (p << 1);
      const float* r0 = V + (size_t)e * DDIM + d0b + dl;
      float4 lo = *(const float4*)(r0);
      float4 hi = *(const float4*)(r0 + DDIM);
      int g = p >> 2, w = p & 3;
      uint32_t w0 = pack2bf(lo.x, hi.x), w1 = pack2bf(lo.y, hi.y);
      uint32_t w2 = pack2bf(lo.z, hi.z), w3 = pack2bf(lo.w, hi.w);
      int d = dl;
      *(uint32_t*)(sV + (d + 0) * 128 + ((g ^ ((d + 0) & 7)) << 4) + (w << 2)) = w0;
      *(uint32_t*)(sV + (d + 1) * 128 + ((g ^ ((d + 1) & 7)) << 4) + (w << 2)) = w1;
      *(uint32_t*)(sV + (d + 2) * 128 + ((g ^ ((d + 2) & 7)) << 4) + (w << 2)) = w2;
      *(uint32_t*)(sV + (d + 3) * 128 + ((g ^ ((d + 3) & 7)) << 4) + (w << 2)) = w3;
    }
    __syncthreads();
#pragma unroll
    for (int kk = 0; kk < 2; kk++) {
      bf16x8 af[4], bfr[4];
#pragma unroll
      for (int mi = 0; mi < 4; mi++) {
        int r = wm * 64 + mi * 16 + l15;
        int g = kk * 4 + quad;
        af[mi] = *(const bf16x8*)(sP + r * 128 + ((g ^ (r & 7)) << 4));
      }
#pragma unroll
      for (int ni = 0; ni < 4; ni++) {
        int d = wn * 64 + ni * 16 + l15;
        int g = kk * 4 + quad;
        bfr[ni] = *(const bf16x8*)(sV + d * 128 + ((g ^ (d & 7)) << 4));
      }
#pragma unroll
      for (int mi = 0; mi < 4; mi++)
#pragma unroll
        for (int ni = 0; ni < 4; ni++)
          acc[mi][ni] = __builtin_amdgcn_mfma_f32_16x16x32_bf16(af[mi], bfr[ni], acc[mi][ni], 0, 0, 0);
    }
    __syncthreads();
  }

#pragma unroll
  for (int mi = 0; mi < 4; mi++)
#pragma unroll
    for (int ni = 0; ni < 4; ni++) {
      int col = d0b + wn * 64 + ni * 16 + l15;
#pragma unroll
      for (int reg = 0; reg < 4; reg++) {
        int row = m0 + wm * 64 + mi * 16 + quad * 4 + reg;
        O[(size_t)row * DDIM + col] = acc[mi][ni][reg];
      }
    }
}

extern "C" void kernel_launch(void* const* d_in, const int* in_sizes, int n_in,
                              void* d_out, int out_size, void* d_ws, size_t ws_size,
                              hipStream_t stream) {
  (void)in_sizes; (void)n_in; (void)out_size; (void)ws_size;
  const float* x1 = (const float*)d_in[0];
  const float* x2 = (const float*)d_in[1];
  float* out = (float*)d_out;

  // workspace: S fp32 (16 MiB) | P_a bf16 (8 MiB) | P_b bf16 (8 MiB)
  float*          S  = (float*)d_ws;
  __hip_bfloat16* Pa = (__hip_bfloat16*)((char*)d_ws + 16777216);
  __hip_bfloat16* Pb = (__hip_bfloat16*)((char*)d_ws + 25165824);

  gemm_qk<<<dim3(4, 4, BATCH), 256, 0, stream>>>(x1, x2, S);
  softmax_rows<<<dim3(BATCH * CDIM), 256, 0, stream>>>(S, Pa);
  softmax_cols<<<dim3(CDIM / 16, BATCH), 256, 0, stream>>>(S, Pb);
  gemm_pv<<<dim3(DDIM / 128, CDIM / 128, BATCH * 2), 256, 0, stream>>>(Pa, Pb, x1, x2, out);
}

// Round 2
// 654.518 us; speedup vs baseline: 1.0680x; 1.0680x over previous
//
#include <hip/hip_runtime.h>
#include <hip/hip_bf16.h>
#include <stdint.h>

#define BATCH 16
#define CDIM  512
#define DDIM  4096
#define SPART ((size_t)BATCH * CDIM * CDIM)   // elements per split-K partial of S

typedef short bf16x8 __attribute__((ext_vector_type(8)));
typedef float f32x4  __attribute__((ext_vector_type(4)));

static __device__ __forceinline__ uint32_t pack2bf(float lo, float hi) {
  __hip_bfloat162 h2 = __float22bfloat162_rn(make_float2(lo, hi));
  uint32_t u; __builtin_memcpy(&u, &h2, 4); return u;
}

// ---------------------------------------------------------------------------
// Phase 1: S_part[kz][b][c][e] = (1/64) * sum_{d in chunk kz} Q[b][c][d]*K[b][e][d]
// Split-K x4 (chunks of 1024) for occupancy: 1024 blocks -> 4 blocks/CU.
// 128x128 tile, BK=64, bf16 MFMA 16x16x32, XOR-granule-swizzled LDS
// (verified conflict-free in round 1: SQ_LDS_BANK_CONFLICT == 0).
// ---------------------------------------------------------------------------
__global__ __launch_bounds__(256) void gemm_qk(const float* __restrict__ Q,
                                               const float* __restrict__ K,
                                               float* __restrict__ S) {
  __shared__ __align__(16) char sA[16384];
  __shared__ __align__(16) char sB[16384];
  const int zz   = blockIdx.z;
  const int kz   = zz & 3;          // split-K chunk
  const int b    = zz >> 2;
  const int c0   = blockIdx.y * 128;
  const int e0   = blockIdx.x * 128;
  const int t    = threadIdx.x;
  const int lane = t & 63;
  const int wave = t >> 6;
  const int wm = wave & 1, wn = wave >> 1;
  const int l15 = lane & 15, quad = lane >> 4;

  const float* Qb = Q + (size_t)b * CDIM * DDIM;
  const float* Kb = K + (size_t)b * CDIM * DDIM;

  f32x4 acc[4][4];
  const f32x4 zero = {0.f, 0.f, 0.f, 0.f};
#pragma unroll
  for (int i = 0; i < 4; i++)
#pragma unroll
    for (int j = 0; j < 4; j++) acc[i][j] = zero;

  const int h     = t & 15;   // half-granule (4 floats) within row
  const int rbase = t >> 4;   // 0..15

  const int dlo = kz * 1024, dhi = dlo + 1024;
  for (int d0 = dlo; d0 < dhi; d0 += 64) {
#pragma unroll
    for (int pass = 0; pass < 8; pass++) {
      int r    = rbase + (pass << 4);           // 0..127
      int g    = h >> 1, half = h & 1;
      int off  = r * 128 + ((g ^ (r & 7)) << 4) + (half << 3);
      float4 qa = *(const float4*)(Qb + (size_t)(c0 + r) * DDIM + d0 + (h << 2));
      float4 kb = *(const float4*)(Kb + (size_t)(e0 + r) * DDIM + d0 + (h << 2));
      *(uint2*)(sA + off) = make_uint2(pack2bf(qa.x, qa.y), pack2bf(qa.z, qa.w));
      *(uint2*)(sB + off) = make_uint2(pack2bf(kb.x, kb.y), pack2bf(kb.z, kb.w));
    }
    __syncthreads();
#pragma unroll
    for (int kk = 0; kk < 2; kk++) {
      bf16x8 af[4], bfr[4];
#pragma unroll
      for (int mi = 0; mi < 4; mi++) {
        int r = wm * 64 + mi * 16 + l15;
        int g = kk * 4 + quad;
        af[mi] = *(const bf16x8*)(sA + r * 128 + ((g ^ (r & 7)) << 4));
      }
#pragma unroll
      for (int ni = 0; ni < 4; ni++) {
        int r = wn * 64 + ni * 16 + l15;
        int g = kk * 4 + quad;
        bfr[ni] = *(const bf16x8*)(sB + r * 128 + ((g ^ (r & 7)) << 4));
      }
#pragma unroll
      for (int mi = 0; mi < 4; mi++)
#pragma unroll
        for (int ni = 0; ni < 4; ni++)
          acc[mi][ni] = __builtin_amdgcn_mfma_f32_16x16x32_bf16(af[mi], bfr[ni], acc[mi][ni], 0, 0, 0);
    }
    __syncthreads();
  }

  float* Sb = S + (size_t)kz * SPART + (size_t)b * CDIM * CDIM;
#pragma unroll
  for (int mi = 0; mi < 4; mi++)
#pragma unroll
    for (int ni = 0; ni < 4; ni++) {
      int col = e0 + wn * 64 + ni * 16 + l15;
#pragma unroll
      for (int reg = 0; reg < 4; reg++) {
        int row = c0 + wm * 64 + mi * 16 + quad * 4 + reg;
        Sb[(size_t)row * CDIM + col] = acc[mi][ni][reg] * 0.015625f;  // 1/64 exact
      }
    }
}

// ---------------------------------------------------------------------------
// Phase 2a: row softmax of (sum of 4 S partials) -> P_a[b][c][e] (bf16).
// ---------------------------------------------------------------------------
__global__ __launch_bounds__(256) void softmax_rows(const float* __restrict__ S,
                                                    __hip_bfloat16* __restrict__ P) {
  const int row = blockIdx.x;  // b*512 + c
  const float* Sr = S + (size_t)row * CDIM;
  const int t = threadIdx.x;
  float v0 = (Sr[t] + Sr[t + SPART]) + (Sr[t + 2 * SPART] + Sr[t + 3 * SPART]);
  float v1 = (Sr[t + 256] + Sr[t + 256 + SPART]) +
             (Sr[t + 256 + 2 * SPART] + Sr[t + 256 + 3 * SPART]);
  float m = fmaxf(v0, v1);
#pragma unroll
  for (int off = 32; off > 0; off >>= 1) m = fmaxf(m, __shfl_down(m, off));
  __shared__ float red[8];
  if ((t & 63) == 0) red[t >> 6] = m;
  __syncthreads();
  m = fmaxf(fmaxf(red[0], red[1]), fmaxf(red[2], red[3]));
  float e0 = __expf(v0 - m), e1 = __expf(v1 - m);
  float s = e0 + e1;
#pragma unroll
  for (int off = 32; off > 0; off >>= 1) s += __shfl_down(s, off);
  if ((t & 63) == 0) red[4 + (t >> 6)] = s;
  __syncthreads();
  s = (red[4] + red[5]) + (red[6] + red[7]);
  float inv = 1.0f / s;
  P[(size_t)row * CDIM + t]       = __float2bfloat16(e0 * inv);
  P[(size_t)row * CDIM + t + 256] = __float2bfloat16(e1 * inv);
}

// ---------------------------------------------------------------------------
// Phase 2b: column softmax of (sum of 4 S partials) -> P_b[b][e][c] (bf16).
// Block = (16 columns e) x (512 rows c), column data cached in LDS.
// ---------------------------------------------------------------------------
__global__ __launch_bounds__(256) void softmax_cols(const float* __restrict__ S,
                                                    __hip_bfloat16* __restrict__ Pb) {
  __shared__ float col[512][17];
  __shared__ float red[16][17];
  __shared__ float invs[16];
  const int b  = blockIdx.y;
  const int e0 = blockIdx.x * 16;
  const int t  = threadIdx.x;
  const int ci = t & 15, ri = t >> 4;
  const float* Sb = S + (size_t)b * CDIM * CDIM + e0;

  float pmax = -1e30f;
#pragma unroll 4
  for (int it = 0; it < 32; it++) {
    int row = ri + (it << 4);
    size_t o = (size_t)row * CDIM + ci;
    float v = (Sb[o] + Sb[o + SPART]) + (Sb[o + 2 * SPART] + Sb[o + 3 * SPART]);
    col[row][ci] = v;
    pmax = fmaxf(pmax, v);
  }
  red[ri][ci] = pmax;
  __syncthreads();
  float M = red[0][ci];
#pragma unroll
  for (int k = 1; k < 16; k++) M = fmaxf(M, red[k][ci]);
  float psum = 0.f;
#pragma unroll 4
  for (int it = 0; it < 32; it++) {
    int row = ri + (it << 4);
    float ev = __expf(col[row][ci] - M);
    col[row][ci] = ev;
    psum += ev;
  }
  __syncthreads();               // protect red reuse
  red[ri][ci] = psum;
  __syncthreads();
  if (ri == 0) {
    float s = 0.f;
#pragma unroll
    for (int k = 0; k < 16; k++) s += red[k][ci];
    invs[ci] = 1.0f / s;
  }
  __syncthreads();
  __hip_bfloat16* Prow = Pb + ((size_t)b * CDIM + e0) * CDIM;
#pragma unroll
  for (int re = 0; re < 16; re++) {
    float inv = invs[re];
    Prow[(size_t)re * CDIM + t]       = __float2bfloat16(col[t][re] * inv);
    Prow[(size_t)re * CDIM + t + 256] = __float2bfloat16(col[t + 256][re] * inv);
  }
}

// ---------------------------------------------------------------------------
// Phase 3: out[b][m][d] = sum_e P[b][m][e] * V[b][e][d]
// dir 0: P=P_a, V=x2 (K), out=out_A.  dir 1: P=P_b, V=x1 (Q), out=out_B.
// V transposed into LDS during staging; thread owns (granule g, 4 d-rows):
// 8x float4 coalesced loads -> 4x b128 LDS writes (was 16x b32 @ 8-way confl).
// ---------------------------------------------------------------------------
__global__ __launch_bounds__(256) void gemm_pv(const __hip_bfloat16* __restrict__ PaAll,
                                               const __hip_bfloat16* __restrict__ PbAll,
                                               const float* __restrict__ X1,
                                               const float* __restrict__ X2,
                                               float* __restrict__ out) {
  __shared__ __align__(16) char sP[16384];
  __shared__ __align__(16) char sV[16384];
  const int zz  = blockIdx.z;
  const int dir = zz & 1, b = zz >> 1;
  const int m0  = blockIdx.y * 128;
  const int d0b = blockIdx.x * 128;
  const int t    = threadIdx.x;
  const int lane = t & 63, wave = t >> 6;
  const int wm = wave & 1, wn = wave >> 1;
  const int l15 = lane & 15, quad = lane >> 4;

  const uint16_t* P = (const uint16_t*)(dir ? PbAll : PaAll) + (size_t)b * CDIM * CDIM;
  const float*    V = (dir ? X1 : X2) + (size_t)b * CDIM * DDIM;
  float*          O = out + (size_t)dir * ((size_t)BATCH * CDIM * DDIM) + (size_t)b * CDIM * DDIM;

  f32x4 acc[4][4];
  const f32x4 zero = {0.f, 0.f, 0.f, 0.f};
#pragma unroll
  for (int i = 0; i < 4; i++)
#pragma unroll
    for (int j = 0; j < 4; j++) acc[i][j] = zero;

  const int cl = t >> 3, gs = t & 7;   // P staging: row, granule
  const int vg = t >> 5;               // V staging: granule 0..7 (e-group of 8)
  const int dg = t & 31;               // V staging: d-group (4 rows)

  for (int e0 = 0; e0 < CDIM; e0 += 64) {
    // stage P tile: 128 rows(m) x 64 e bf16, xor-swizzled granules
#pragma unroll
    for (int j = 0; j < 4; j++) {
      int c  = cl + (j << 5);
      int gl = gs ^ (c & 7);
      uint4 v = *(const uint4*)(P + (size_t)(m0 + c) * CDIM + e0 + (gl << 3));
      *(uint4*)(sP + c * 128 + (gs << 4)) = v;
    }
    // stage V^T tile: LDS row d (128 rows) holds 64 e as bf16 pairs.
    // thread (vg,dg): loads V[e0+8*vg+j][d0b+4*dg .. +3], j=0..7
    {
      const float* vb = V + (size_t)(e0 + (vg << 3)) * DDIM + d0b + (dg << 2);
      float4 L0 = *(const float4*)(vb);
      float4 L1 = *(const float4*)(vb + DDIM);
      float4 L2 = *(const float4*)(vb + 2 * DDIM);
      float4 L3 = *(const float4*)(vb + 3 * DDIM);
      float4 L4 = *(const float4*)(vb + 4 * DDIM);
      float4 L5 = *(const float4*)(vb + 5 * DDIM);
      float4 L6 = *(const float4*)(vb + 6 * DDIM);
      float4 L7 = *(const float4*)(vb + 7 * DDIM);
      const float* p0 = (const float*)&L0; const float* p1 = (const float*)&L1;
      const float* p2 = (const float*)&L2; const float* p3 = (const float*)&L3;
      const float* p4 = (const float*)&L4; const float* p5 = (const float*)&L5;
      const float* p6 = (const float*)&L6; const float* p7 = (const float*)&L7;
#pragma unroll
      for (int dd = 0; dd < 4; dd++) {
        int d = (dg << 2) + dd;
        uint4 w;
        w.x = pack2bf(p0[dd], p1[dd]);
        w.y = pack2bf(p2[dd], p3[dd]);
        w.z = pack2bf(p4[dd], p5[dd]);
        w.w = pack2bf(p6[dd], p7[dd]);
        *(uint4*)(sV + d * 128 + ((vg ^ (d & 7)) << 4)) = w;
      }
    }
    __syncthreads();
#pragma unroll
    for (int kk = 0; kk < 2; kk++) {
      bf16x8 af[4], bfr[4];
#pragma unroll
      for (int mi = 0; mi < 4; mi++) {
        int r = wm * 64 + mi * 16 + l15;
        int g = kk * 4 + quad;
        af[mi] = *(const bf16x8*)(sP + r * 128 + ((g ^ (r & 7)) << 4));
      }
#pragma unroll
      for (int ni = 0; ni < 4; ni++) {
        int d = wn * 64 + ni * 16 + l15;
        int g = kk * 4 + quad;
        bfr[ni] = *(const bf16x8*)(sV + d * 128 + ((g ^ (d & 7)) << 4));
      }
#pragma unroll
      for (int mi = 0; mi < 4; mi++)
#pragma unroll
        for (int ni = 0; ni < 4; ni++)
          acc[mi][ni] = __builtin_amdgcn_mfma_f32_16x16x32_bf16(af[mi], bfr[ni], acc[mi][ni], 0, 0, 0);
    }
    __syncthreads();
  }

#pragma unroll
  for (int mi = 0; mi < 4; mi++)
#pragma unroll
    for (int ni = 0; ni < 4; ni++) {
      int col = d0b + wn * 64 + ni * 16 + l15;
#pragma unroll
      for (int reg = 0; reg < 4; reg++) {
        int row = m0 + wm * 64 + mi * 16 + quad * 4 + reg;
        O[(size_t)row * DDIM + col] = acc[mi][ni][reg];
      }
    }
}

extern "C" void kernel_launch(void* const* d_in, const int* in_sizes, int n_in,
                              void* d_out, int out_size, void* d_ws, size_t ws_size,
                              hipStream_t stream) {
  (void)in_sizes; (void)n_in; (void)out_size; (void)ws_size;
  const float* x1 = (const float*)d_in[0];
  const float* x2 = (const float*)d_in[1];
  float* out = (float*)d_out;

  // S partials (4 x 16 MiB fp32) live in the FRONT of d_out (268 MB):
  // written by gemm_qk, consumed by the softmax kernels, then overwritten
  // by gemm_pv (stream-ordered, so no hazard). d_ws holds only Pa/Pb (16 MiB).
  float*          S  = (float*)d_out;
  __hip_bfloat16* Pa = (__hip_bfloat16*)d_ws;
  __hip_bfloat16* Pb = (__hip_bfloat16*)((char*)d_ws + 8388608);

  gemm_qk<<<dim3(4, 4, BATCH * 4), 256, 0, stream>>>(x1, x2, S);
  softmax_rows<<<dim3(BATCH * CDIM), 256, 0, stream>>>(S, Pa);
  softmax_cols<<<dim3(CDIM / 16, BATCH), 256, 0, stream>>>(S, Pb);
  gemm_pv<<<dim3(DDIM / 128, CDIM / 128, BATCH * 2), 256, 0, stream>>>(Pa, Pb, x1, x2, out);
}